// Round 1
// baseline (127.366 us; speedup 1.0000x reference)
//
#include <hip/hip_runtime.h>
#include <hip/hip_bf16.h>

// ---------------------------------------------------------------------------
// LossNet: x (12288,128) fp32 -> scalar loss.  bsz=4096.
// 5 matrices (zx/zy folded into colsums of xz/yz):
//   task 0 xx, 1 yy, 2 xy, 3 xz (+colsum->s_zx), 4 yz (+colsum->s_zy)
// Fragment-native layout (R6): every MFMA A/B fragment is ONE coalesced
// global_load_dwordx4; no LDS staging, no hot-loop barriers.
// R15: expsim hot loop = R10 verbatim (measured best).  NEW: reduce_kernel
// fused into expsim via device-scope ticket -- the last 16 blocks to finish
// become the 16 reducer blocks (release: barrier-drain + __threadfence
// (buffer_wbl2) + atomicAdd; acquire: atomic spin + __threadfence
// (buffer_inv)).  Removes one kernel node + serialization gap (~4 us serial
// tail).  No deadlock: rank>=GRID-16 implies <=15 blocks outstanding vs
// >=256 resident slots.  R12/R13 post-mortem: triangular xx/yy savings are
// grid-quantization-bound -> regressed.  The ~4 ns per 128x64-tile expsim
// constant survived six structure falsifications (LDS-staged / direct /
// prefetch / reuse / pipelined / 64-row waves) -> structural plateau.
// Timed window is ~44% fixed harness poison fill (268 MB @ ~80% HBM peak).
// All reductions exclusive non-atomic stores (R3: atomics serialized).
// exp = __builtin_amdgcn_exp2f on prescaled inputs (1 inst).
// ---------------------------------------------------------------------------

typedef __attribute__((ext_vector_type(8))) short short8;   // 8 x bf16
typedef __attribute__((ext_vector_type(4))) float floatx4;  // MFMA acc

#define D   128
#define BSZ 4096
// expsim grid: 5 tasks x 32 rb(128 rows) x 8 cb(512 cols) = 1280 blocks
#define GRID_EXPSIM (5 * 32 * 8)
#define RED_BLOCKS  16

// ---------------------------------------------------------------------------
// Kernel 1: row-normalize fp32 -> bf16 into fragment-native layout,
// prescaled by sqrt(10*log2(e)).  One wave per row.  Also zeroes out[0]
// and the ticket (workspace is harness-poisoned every iteration).
// ---------------------------------------------------------------------------
__global__ __launch_bounds__(256) void normalize_kernel(
    const float* __restrict__ x, __hip_bfloat162* __restrict__ xnf2,
    float* __restrict__ out, unsigned int* __restrict__ ticket, int rows) {
  int tid = threadIdx.x;
  if (blockIdx.x == 0 && tid == 0) {
    out[0] = 0.0f;
    ticket[0] = 0u;
  }

  int row  = blockIdx.x * 4 + (tid >> 6);
  int lane = tid & 63;
  if (row >= rows) return;
  const float2* xr = (const float2*)(x + (size_t)row * D);
  float2 v = xr[lane];
  float s = v.x * v.x + v.y * v.y;
#pragma unroll
  for (int off = 1; off < 64; off <<= 1) s += __shfl_xor(s, off, 64);
  // sqrt(10 / ln 2): dot(a,b) = 10*log2(e)*cos -> e^(10 cos) = exp2(dot)
  float scale = 3.7982825470322528f / fmaxf(sqrtf(s), 1e-12f);
  __hip_bfloat162 h;
  h.x = __float2bfloat16(v.x * scale);
  h.y = __float2bfloat16(v.y * scale);
  // fragment-native scatter: k0 = lane*2
  // short idx = g*2048 + kk*512 + (quad*16 + (row&15))*8 + j   (as bf162: /2)
  int g    = row >> 4;
  int kk   = lane >> 4;            // k0>>5
  int quad = (lane >> 2) & 3;      // (k0>>3)&3
  int jj   = lane & 3;             // (k0&7)/2
  xnf2[g * 1024 + kk * 256 + (quad * 16 + (row & 15)) * 4 + jj] = h;
}

// ---------------------------------------------------------------------------
// 16-col subtile epilogue for a 32-row wave: 8 exps, rowsum adds, optional
// colsum (quad-reduce -> LDS slot, written once), diag when st==st0+mi.
// C/D layout: col=lm, row=quad*4+reg  [m89-verified]
// ---------------------------------------------------------------------------
template <bool COL>
__device__ __forceinline__ void epi16(
    const floatx4 (&ac)[2], float (&rs)[2][4], int st,
    bool dgw, int st0, int rowg0, int quad, int lm, int w,
    float* __restrict__ diag_ptr, float* __restrict__ csLDS) {
  float cs = 0.f;
#pragma unroll
  for (int mi = 0; mi < 2; mi++) {
    bool dd = dgw && (st == st0 + mi);   // wave-uniform
#pragma unroll
    for (int r = 0; r < 4; r++) {
      float e = __builtin_amdgcn_exp2f(ac[mi][r]);  // v_exp_f32
      rs[mi][r] += e;
      if (COL) cs += e;
      if (dd && lm == quad * 4 + r)
        diag_ptr[rowg0 + mi * 16 + quad * 4 + r] = e;
    }
  }
  if (COL) {
    cs += __shfl_xor(cs, 16, 64);
    cs += __shfl_xor(cs, 32, 64);
    if (quad == 0) csLDS[w * 512 + st * 16 + lm] = cs;
  }
}

#define MFMA8(AC, BF)                                                        \
  _Pragma("unroll") for (int kk = 0; kk < 4; kk++)                           \
      _Pragma("unroll") for (int mi = 0; mi < 2; mi++)                       \
          AC[mi] = __builtin_amdgcn_mfma_f32_16x16x32_bf16(                  \
              afrag[mi][kk], BF[kk], (kk == 0) ? z4 : AC[mi], 0, 0, 0);

// ---------------------------------------------------------------------------
// Wave main loop: 32 rows x 512 cols as 32 subtiles of 16 cols, software-
// pipelined (epi of s-1 between MFMAs of s / loads of s+1).
// ---------------------------------------------------------------------------
template <bool COL>
__device__ __forceinline__ void wave_loop(
    const short8* __restrict__ xnf8, int gA, int gB0, int rowg0,
    int st0, bool dgw, int quad, int lm, int w, int lane,
    float (&rs)[2][4], float* __restrict__ diag_ptr,
    float* __restrict__ csLDS) {
  const floatx4 z4 = {0.f, 0.f, 0.f, 0.f};

  short8 afrag[2][4];
#pragma unroll
  for (int mi = 0; mi < 2; mi++)
#pragma unroll
    for (int kk = 0; kk < 4; kk++)
      afrag[mi][kk] = xnf8[(size_t)(gA + mi) * 256 + kk * 64 + lane];

  const short8* bp = xnf8 + (size_t)gB0 * 256 + lane;
  short8 bf0[4], bf1[4];
#pragma unroll
  for (int kk = 0; kk < 4; kk++) bf0[kk] = bp[kk * 64];
#pragma unroll
  for (int kk = 0; kk < 4; kk++) bf1[kk] = bp[256 + kk * 64];

  floatx4 ac0[2], ac1[2];
  MFMA8(ac0, bf0)   // st 0

#pragma unroll 1
  for (int k = 0; k < 15; k++) {
    int sB = 2 * k + 2;
    MFMA8(ac1, bf1)   // st sB-1
#pragma unroll
    for (int kk = 0; kk < 4; kk++) bf0[kk] = bp[(size_t)sB * 256 + kk * 64];
    epi16<COL>(ac0, rs, sB - 2, dgw, st0, rowg0, quad, lm, w, diag_ptr, csLDS);
    MFMA8(ac0, bf0)   // st sB
#pragma unroll
    for (int kk = 0; kk < 4; kk++) bf1[kk] = bp[(size_t)(sB + 1) * 256 + kk * 64];
    epi16<COL>(ac1, rs, sB - 1, dgw, st0, rowg0, quad, lm, w, diag_ptr, csLDS);
  }
  // tail: st 31 from bf1; epi st 30 (ac0), st 31 (ac1)
  MFMA8(ac1, bf1)
  epi16<COL>(ac0, rs, 30, dgw, st0, rowg0, quad, lm, w, diag_ptr, csLDS);
  epi16<COL>(ac1, rs, 31, dgw, st0, rowg0, quad, lm, w, diag_ptr, csLDS);
}

// ---------------------------------------------------------------------------
// Kernel 2: exp-sim.  block = (task, rb of 128 rows, cb of 512 cols);
// wave w owns rows rb*128+w*32..+32, all 512 cols.  4 waves share B (L1).
// NOTE: plain __launch_bounds__(256) — min-waves cap spills (R2).
// Tail: ticket protocol; last RED_BLOCKS blocks perform the final loss
// reduction (previously a separate 16-block kernel).
// ---------------------------------------------------------------------------
__global__ __launch_bounds__(256) void expsim_kernel(
    const short8* __restrict__ xnf8,
    float* __restrict__ srow,   // [5][128][8][32] exclusive
    float* __restrict__ scol,   // [2][32][4096] exclusive
    float* __restrict__ diag,   // [5][4096] exclusive
    float* __restrict__ out,
    unsigned int* __restrict__ ticket) {
  __shared__ float csLDS[4 * 512];   // colsum accum, tasks 3-4 only
  __shared__ unsigned int sh_rank;

  int tid = threadIdx.x;
  int bx  = blockIdx.x;
  int task = bx >> 8;          // 256 blocks per task
  int rem  = bx & 255;
  int rb   = rem >> 3;         // 32 row-blocks of 128
  int cb   = rem & 7;          // 8 col-strips of 512

  const int aoff_t[5] = {0, 1, 0, 0, 1};
  const int boff_t[5] = {0, 1, 1, 2, 2};
  bool col_en = (task >= 3);

  int w    = tid >> 6;
  int lane = tid & 63;
  int quad = lane >> 4;
  int lm   = lane & 15;
  int rowg0 = rb * 128 + w * 32;

  int gA  = aoff_t[task] * 256 + rb * 8 + w * 2;
  int gB0 = boff_t[task] * 256 + cb * 32;
  int st0 = rb * 8 + w * 2 - cb * 32;   // diag subtile (mi=0) if in range
  bool dgw = (st0 >= 0 && st0 < 32);

  float* diag_ptr = diag + task * BSZ;

  float rs[2][4];
#pragma unroll
  for (int mi = 0; mi < 2; mi++)
#pragma unroll
    for (int r = 0; r < 4; r++) rs[mi][r] = 0.0f;

  if (col_en)
    wave_loop<true>(xnf8, gA, gB0, rowg0, st0, dgw, quad, lm, w, lane, rs,
                    diag_ptr, csLDS);
  else
    wave_loop<false>(xnf8, gA, gB0, rowg0, st0, dgw, quad, lm, w, lane, rs,
                     diag_ptr, csLDS);

  // ---- row-sum flush: reduce over lm within quad, exclusive store ----
  float* sp = srow + (((size_t)task * 128 + rb * 4 + w) * 8 + cb) * 32;
#pragma unroll
  for (int mi = 0; mi < 2; mi++) {
#pragma unroll
    for (int r = 0; r < 4; r++) {
      float v = rs[mi][r];
      v += __shfl_xor(v, 1, 64);
      v += __shfl_xor(v, 2, 64);
      v += __shfl_xor(v, 4, 64);
      v += __shfl_xor(v, 8, 64);
      if (lm == 0) sp[mi * 16 + quad * 4 + r] = v;
    }
  }

  // ---- col-sum flush: one barrier, cross-wave LDS reduce, exclusive ----
  if (col_en) {
    __syncthreads();
    float* scp = scol + ((size_t)((task - 3) * 32 + rb)) * BSZ + cb * 512;
    for (int c = tid; c < 512; c += 256)
      scp[c] = csLDS[c] + csLDS[512 + c] + csLDS[1024 + c] + csLDS[1536 + c];
  }

  // ---- ticket: release this block's stores, grab completion rank ----
  // __syncthreads() implies s_waitcnt vmcnt(0): all block stores are in L2.
  // __threadfence() (agent release) writes back this XCD's L2 so reducer
  // blocks on other XCDs can observe the data (G16 cross-XCD protocol).
  __syncthreads();
  if (tid == 0) {
    __threadfence();
    sh_rank = atomicAdd(ticket, 1u);
  }
  __syncthreads();
  unsigned int rank = sh_rank;
  if (rank < (unsigned)(GRID_EXPSIM - RED_BLOCKS)) return;

  // ---- last 16 blocks: wait for everyone, then do the final reduction ----
  if (tid == 0) {
    // atomic RMW poll: guaranteed to observe remote increments (no stale L1)
    while (atomicAdd(ticket, 0u) < (unsigned)GRID_EXPSIM)
      __builtin_amdgcn_s_sleep(1);
  }
  __syncthreads();
  __threadfence();   // acquire: invalidate stale L1/L2 before reading srow/scol/diag

  int rblk = (int)(rank - (unsigned)(GRID_EXPSIM - RED_BLOCKS));  // 0..15
  int i    = rblk * 256 + tid;                                    // 0..4095
  int strip = i >> 5, rloc = i & 31;

  float s[5];
#pragma unroll
  for (int t = 0; t < 5; t++) {
    float a = 0.f;
#pragma unroll
    for (int cc = 0; cc < 8; cc++)
      a += srow[(((size_t)t * 128 + strip) * 8 + cc) * 32 + rloc];
    s[t] = a;
  }
  float s_zx = 0.f, s_zy = 0.f;
#pragma unroll 8
  for (int rr = 0; rr < 32; rr++) {
    s_zx += scol[(size_t)rr * BSZ + i];
    s_zy += scol[(size_t)(32 + rr) * BSZ + i];
  }
  float d_xx = diag[0 * BSZ + i], d_yy = diag[1 * BSZ + i];
  float d_xy = diag[2 * BSZ + i], d_ax = diag[3 * BSZ + i];
  float d_ay = diag[4 * BSZ + i];

  float denom = (s[2] - d_xy) + (s[0] - d_xx) + (s[1] - d_yy);
  float tloc = -2.0f * __logf(d_xy / denom);
  tloc -= __logf(d_ax / (s[3] - d_ax));
  tloc -= __logf(d_ay / (s[4] - d_ay));
  tloc -= __logf(d_ax / (s_zx - d_ax));   // d_zx == d_ax
  tloc -= __logf(d_ay / (s_zy - d_ay));   // d_zy == d_ay

  // reuse csLDS as the block-reduction scratch (safe: all waves past the
  // post-flush __syncthreads above)
  float* red = csLDS;
  red[tid] = tloc;
  __syncthreads();
  for (int st = 128; st > 0; st >>= 1) {
    if (tid < st) red[tid] += red[tid + st];
    __syncthreads();
  }
  if (tid == 0) atomicAdd(out, red[0] / (float)BSZ);
}

// ---------------------------------------------------------------------------
extern "C" void kernel_launch(void* const* d_in, const int* in_sizes, int n_in,
                              void* d_out, int out_size, void* d_ws, size_t ws_size,
                              hipStream_t stream) {
  const float* x = (const float*)d_in[0];
  int rows = in_sizes[0] / D;   // 12288

  char*  ws       = (char*)d_ws;
  short* xnf      = (short*)ws;                        // 12288*128 bf16: 3 MiB
  size_t xn_bytes = (size_t)rows * D * sizeof(short);
  float* srow     = (float*)(ws + xn_bytes);           // [5][128][8][32]: 640 KiB
  float* scol     = srow + 5 * 128 * 8 * 32;           // [2][32][4096]: 1 MiB
  float* diag     = scol + 2 * 32 * BSZ;               // [5][4096]: 80 KiB
  unsigned int* ticket = (unsigned int*)(diag + 5 * BSZ);

  normalize_kernel<<<rows / 4, 256, 0, stream>>>(
      x, (__hip_bfloat162*)xnf, (float*)d_out, ticket, rows);
  expsim_kernel<<<GRID_EXPSIM, 256, 0, stream>>>(
      (const short8*)xnf, srow, scol, diag, (float*)d_out, ticket);
}

// Round 2
// 100.793 us; speedup vs baseline: 1.2636x; 1.2636x over previous
//
#include <hip/hip_runtime.h>
#include <hip/hip_bf16.h>

// ---------------------------------------------------------------------------
// LossNet: x (12288,128) fp32 -> scalar loss.  bsz=4096.
// 5 matrices (zx/zy folded into colsums of xz/yz):
//   task 0 xx, 1 yy, 2 xy, 3 xz (+colsum->s_zx), 4 yz (+colsum->s_zy)
// Fragment-native layout (R6): every MFMA A/B fragment is ONE coalesced
// global_load_dwordx4; no LDS staging, no hot-loop barriers.
// R16: expsim hot loop = R10 verbatim.  Fused reduce tail kept, but the
// R15 protocol (per-block __threadfence = buffer_wbl2 + buffer_inv) is
// replaced by a fence-free release: R15's per-block L2 INVALIDATE evicted
// the 3 MiB xnf working set under 1279 other blocks -> B loads fell to
// L3 latency, MfmaUtil 21->10%, FETCH 3x, expsim +38 us.  Now:
//   writers : srow/scol/diag via relaxed AGENT-scope stores (sc0 sc1,
//             write-through, no bulk cache ops), __syncthreads (vmcnt
//             drain) -> relaxed agent atomicAdd(ticket).
//   reducers: relaxed agent LOAD spin (no RMW ownership ping-pong),
//             then relaxed agent loads of srow/scol/diag (bypass stale L2).
// No threadfence anywhere; zero cache-wide maintenance in-kernel.
// No deadlock: rank>=GRID-16 implies <=15 blocks outstanding vs >=256
// resident slots.  R12/R13: triangular xx/yy is grid-quantization-bound ->
// regressed.  The ~4 ns per 128x64-tile expsim constant survived six
// structure falsifications -> structural plateau.  Timed window is ~44%
// fixed harness poison fill (268 MB @ ~80% HBM peak).
// exp = __builtin_amdgcn_exp2f on prescaled inputs (1 inst).
// ---------------------------------------------------------------------------

typedef __attribute__((ext_vector_type(8))) short short8;   // 8 x bf16
typedef __attribute__((ext_vector_type(4))) float floatx4;  // MFMA acc

#define D   128
#define BSZ 4096
// expsim grid: 5 tasks x 32 rb(128 rows) x 8 cb(512 cols) = 1280 blocks
#define GRID_EXPSIM (5 * 32 * 8)
#define RED_BLOCKS  16

#define ST_AGENT(p, v) \
  __hip_atomic_store((p), (v), __ATOMIC_RELAXED, __HIP_MEMORY_SCOPE_AGENT)
#define LD_AGENT(p) \
  __hip_atomic_load((p), __ATOMIC_RELAXED, __HIP_MEMORY_SCOPE_AGENT)

// ---------------------------------------------------------------------------
// Kernel 1: row-normalize fp32 -> bf16 into fragment-native layout,
// prescaled by sqrt(10*log2(e)).  One wave per row.  Also zeroes out[0]
// and the ticket (workspace is harness-poisoned every iteration).
// ---------------------------------------------------------------------------
__global__ __launch_bounds__(256) void normalize_kernel(
    const float* __restrict__ x, __hip_bfloat162* __restrict__ xnf2,
    float* __restrict__ out, unsigned int* __restrict__ ticket, int rows) {
  int tid = threadIdx.x;
  if (blockIdx.x == 0 && tid == 0) {
    out[0] = 0.0f;
    ticket[0] = 0u;
  }

  int row  = blockIdx.x * 4 + (tid >> 6);
  int lane = tid & 63;
  if (row >= rows) return;
  const float2* xr = (const float2*)(x + (size_t)row * D);
  float2 v = xr[lane];
  float s = v.x * v.x + v.y * v.y;
#pragma unroll
  for (int off = 1; off < 64; off <<= 1) s += __shfl_xor(s, off, 64);
  // sqrt(10 / ln 2): dot(a,b) = 10*log2(e)*cos -> e^(10 cos) = exp2(dot)
  float scale = 3.7982825470322528f / fmaxf(sqrtf(s), 1e-12f);
  __hip_bfloat162 h;
  h.x = __float2bfloat16(v.x * scale);
  h.y = __float2bfloat16(v.y * scale);
  // fragment-native scatter: k0 = lane*2
  // short idx = g*2048 + kk*512 + (quad*16 + (row&15))*8 + j   (as bf162: /2)
  int g    = row >> 4;
  int kk   = lane >> 4;            // k0>>5
  int quad = (lane >> 2) & 3;      // (k0>>3)&3
  int jj   = lane & 3;             // (k0&7)/2
  xnf2[g * 1024 + kk * 256 + (quad * 16 + (row & 15)) * 4 + jj] = h;
}

// ---------------------------------------------------------------------------
// 16-col subtile epilogue for a 32-row wave: 8 exps, rowsum adds, optional
// colsum (quad-reduce -> LDS slot, written once), diag when st==st0+mi.
// C/D layout: col=lm, row=quad*4+reg  [m89-verified]
// diag store is agent-scope (write-through) so reducers can read it
// without any cache invalidation.
// ---------------------------------------------------------------------------
template <bool COL>
__device__ __forceinline__ void epi16(
    const floatx4 (&ac)[2], float (&rs)[2][4], int st,
    bool dgw, int st0, int rowg0, int quad, int lm, int w,
    float* __restrict__ diag_ptr, float* __restrict__ csLDS) {
  float cs = 0.f;
#pragma unroll
  for (int mi = 0; mi < 2; mi++) {
    bool dd = dgw && (st == st0 + mi);   // wave-uniform
#pragma unroll
    for (int r = 0; r < 4; r++) {
      float e = __builtin_amdgcn_exp2f(ac[mi][r]);  // v_exp_f32
      rs[mi][r] += e;
      if (COL) cs += e;
      if (dd && lm == quad * 4 + r)
        ST_AGENT(&diag_ptr[rowg0 + mi * 16 + quad * 4 + r], e);
    }
  }
  if (COL) {
    cs += __shfl_xor(cs, 16, 64);
    cs += __shfl_xor(cs, 32, 64);
    if (quad == 0) csLDS[w * 512 + st * 16 + lm] = cs;
  }
}

#define MFMA8(AC, BF)                                                        \
  _Pragma("unroll") for (int kk = 0; kk < 4; kk++)                           \
      _Pragma("unroll") for (int mi = 0; mi < 2; mi++)                       \
          AC[mi] = __builtin_amdgcn_mfma_f32_16x16x32_bf16(                  \
              afrag[mi][kk], BF[kk], (kk == 0) ? z4 : AC[mi], 0, 0, 0);

// ---------------------------------------------------------------------------
// Wave main loop: 32 rows x 512 cols as 32 subtiles of 16 cols, software-
// pipelined (epi of s-1 between MFMAs of s / loads of s+1).
// ---------------------------------------------------------------------------
template <bool COL>
__device__ __forceinline__ void wave_loop(
    const short8* __restrict__ xnf8, int gA, int gB0, int rowg0,
    int st0, bool dgw, int quad, int lm, int w, int lane,
    float (&rs)[2][4], float* __restrict__ diag_ptr,
    float* __restrict__ csLDS) {
  const floatx4 z4 = {0.f, 0.f, 0.f, 0.f};

  short8 afrag[2][4];
#pragma unroll
  for (int mi = 0; mi < 2; mi++)
#pragma unroll
    for (int kk = 0; kk < 4; kk++)
      afrag[mi][kk] = xnf8[(size_t)(gA + mi) * 256 + kk * 64 + lane];

  const short8* bp = xnf8 + (size_t)gB0 * 256 + lane;
  short8 bf0[4], bf1[4];
#pragma unroll
  for (int kk = 0; kk < 4; kk++) bf0[kk] = bp[kk * 64];
#pragma unroll
  for (int kk = 0; kk < 4; kk++) bf1[kk] = bp[256 + kk * 64];

  floatx4 ac0[2], ac1[2];
  MFMA8(ac0, bf0)   // st 0

#pragma unroll 1
  for (int k = 0; k < 15; k++) {
    int sB = 2 * k + 2;
    MFMA8(ac1, bf1)   // st sB-1
#pragma unroll
    for (int kk = 0; kk < 4; kk++) bf0[kk] = bp[(size_t)sB * 256 + kk * 64];
    epi16<COL>(ac0, rs, sB - 2, dgw, st0, rowg0, quad, lm, w, diag_ptr, csLDS);
    MFMA8(ac0, bf0)   // st sB
#pragma unroll
    for (int kk = 0; kk < 4; kk++) bf1[kk] = bp[(size_t)(sB + 1) * 256 + kk * 64];
    epi16<COL>(ac1, rs, sB - 1, dgw, st0, rowg0, quad, lm, w, diag_ptr, csLDS);
  }
  // tail: st 31 from bf1; epi st 30 (ac0), st 31 (ac1)
  MFMA8(ac1, bf1)
  epi16<COL>(ac0, rs, 30, dgw, st0, rowg0, quad, lm, w, diag_ptr, csLDS);
  epi16<COL>(ac1, rs, 31, dgw, st0, rowg0, quad, lm, w, diag_ptr, csLDS);
}

// ---------------------------------------------------------------------------
// Kernel 2: exp-sim.  block = (task, rb of 128 rows, cb of 512 cols);
// wave w owns rows rb*128+w*32..+32, all 512 cols.  4 waves share B (L1).
// NOTE: plain __launch_bounds__(256) — min-waves cap spills (R2).
// Tail: fence-free ticket; last RED_BLOCKS blocks do the final reduction.
// ---------------------------------------------------------------------------
__global__ __launch_bounds__(256) void expsim_kernel(
    const short8* __restrict__ xnf8,
    float* __restrict__ srow,   // [5][128][8][32] exclusive
    float* __restrict__ scol,   // [2][32][4096] exclusive
    float* __restrict__ diag,   // [5][4096] exclusive
    float* __restrict__ out,
    unsigned int* __restrict__ ticket) {
  __shared__ float csLDS[4 * 512];   // colsum accum, tasks 3-4 only
  __shared__ unsigned int sh_rank;

  int tid = threadIdx.x;
  int bx  = blockIdx.x;
  int task = bx >> 8;          // 256 blocks per task
  int rem  = bx & 255;
  int rb   = rem >> 3;         // 32 row-blocks of 128
  int cb   = rem & 7;          // 8 col-strips of 512

  const int aoff_t[5] = {0, 1, 0, 0, 1};
  const int boff_t[5] = {0, 1, 1, 2, 2};
  bool col_en = (task >= 3);

  int w    = tid >> 6;
  int lane = tid & 63;
  int quad = lane >> 4;
  int lm   = lane & 15;
  int rowg0 = rb * 128 + w * 32;

  int gA  = aoff_t[task] * 256 + rb * 8 + w * 2;
  int gB0 = boff_t[task] * 256 + cb * 32;
  int st0 = rb * 8 + w * 2 - cb * 32;   // diag subtile (mi=0) if in range
  bool dgw = (st0 >= 0 && st0 < 32);

  float* diag_ptr = diag + task * BSZ;

  float rs[2][4];
#pragma unroll
  for (int mi = 0; mi < 2; mi++)
#pragma unroll
    for (int r = 0; r < 4; r++) rs[mi][r] = 0.0f;

  if (col_en)
    wave_loop<true>(xnf8, gA, gB0, rowg0, st0, dgw, quad, lm, w, lane, rs,
                    diag_ptr, csLDS);
  else
    wave_loop<false>(xnf8, gA, gB0, rowg0, st0, dgw, quad, lm, w, lane, rs,
                     diag_ptr, csLDS);

  // ---- row-sum flush: reduce over lm within quad, agent-scope store ----
  float* sp = srow + (((size_t)task * 128 + rb * 4 + w) * 8 + cb) * 32;
#pragma unroll
  for (int mi = 0; mi < 2; mi++) {
#pragma unroll
    for (int r = 0; r < 4; r++) {
      float v = rs[mi][r];
      v += __shfl_xor(v, 1, 64);
      v += __shfl_xor(v, 2, 64);
      v += __shfl_xor(v, 4, 64);
      v += __shfl_xor(v, 8, 64);
      if (lm == 0) ST_AGENT(&sp[mi * 16 + quad * 4 + r], v);
    }
  }

  // ---- col-sum flush: one barrier, cross-wave LDS reduce ----
  if (col_en) {
    __syncthreads();
    float* scp = scol + ((size_t)((task - 3) * 32 + rb)) * BSZ + cb * 512;
    for (int c = tid; c < 512; c += 256)
      ST_AGENT(&scp[c],
               csLDS[c] + csLDS[512 + c] + csLDS[1024 + c] + csLDS[1536 + c]);
  }

  // ---- ticket: release rank.  __syncthreads drains vmcnt(0), so all this
  // block's agent-scope (write-through) stores are at the coherent point
  // before the relaxed agent atomicAdd publishes the rank.  NO fence ->
  // no buffer_wbl2 / buffer_inv -> other blocks' L2-resident xnf survives.
  __syncthreads();
  if (tid == 0)
    sh_rank = __hip_atomic_fetch_add(ticket, 1u, __ATOMIC_RELAXED,
                                     __HIP_MEMORY_SCOPE_AGENT);
  __syncthreads();
  unsigned int rank = sh_rank;
  if (rank < (unsigned)(GRID_EXPSIM - RED_BLOCKS)) return;

  // ---- last 16 blocks: LOAD-spin (no RMW ownership ping-pong) ----
  if (tid == 0) {
    while (LD_AGENT(ticket) < (unsigned)GRID_EXPSIM)
      __builtin_amdgcn_s_sleep(2);
  }
  __syncthreads();

  // All reads below are agent-scope coherent loads (sc0 sc1): they bypass
  // any stale L1/L2 lines, so no acquire invalidate is needed.
  int rblk = (int)(rank - (unsigned)(GRID_EXPSIM - RED_BLOCKS));  // 0..15
  int i    = rblk * 256 + tid;                                    // 0..4095
  int strip = i >> 5, rloc = i & 31;

  float s[5];
#pragma unroll
  for (int t = 0; t < 5; t++) {
    float a = 0.f;
#pragma unroll
    for (int cc = 0; cc < 8; cc++)
      a += LD_AGENT(&srow[(((size_t)t * 128 + strip) * 8 + cc) * 32 + rloc]);
    s[t] = a;
  }
  float s_zx = 0.f, s_zy = 0.f;
#pragma unroll 8
  for (int rr = 0; rr < 32; rr++) {
    s_zx += LD_AGENT(&scol[(size_t)rr * BSZ + i]);
    s_zy += LD_AGENT(&scol[(size_t)(32 + rr) * BSZ + i]);
  }
  float d_xx = LD_AGENT(&diag[0 * BSZ + i]);
  float d_yy = LD_AGENT(&diag[1 * BSZ + i]);
  float d_xy = LD_AGENT(&diag[2 * BSZ + i]);
  float d_ax = LD_AGENT(&diag[3 * BSZ + i]);
  float d_ay = LD_AGENT(&diag[4 * BSZ + i]);

  float denom = (s[2] - d_xy) + (s[0] - d_xx) + (s[1] - d_yy);
  float tloc = -2.0f * __logf(d_xy / denom);
  tloc -= __logf(d_ax / (s[3] - d_ax));
  tloc -= __logf(d_ay / (s[4] - d_ay));
  tloc -= __logf(d_ax / (s_zx - d_ax));   // d_zx == d_ax
  tloc -= __logf(d_ay / (s_zy - d_ay));   // d_zy == d_ay

  // reuse csLDS as the block-reduction scratch (safe: all waves past the
  // post-flush __syncthreads above)
  float* red = csLDS;
  red[tid] = tloc;
  __syncthreads();
  for (int st = 128; st > 0; st >>= 1) {
    if (tid < st) red[tid] += red[tid + st];
    __syncthreads();
  }
  if (tid == 0) atomicAdd(out, red[0] / (float)BSZ);
}

// ---------------------------------------------------------------------------
extern "C" void kernel_launch(void* const* d_in, const int* in_sizes, int n_in,
                              void* d_out, int out_size, void* d_ws, size_t ws_size,
                              hipStream_t stream) {
  const float* x = (const float*)d_in[0];
  int rows = in_sizes[0] / D;   // 12288

  char*  ws       = (char*)d_ws;
  short* xnf      = (short*)ws;                        // 12288*128 bf16: 3 MiB
  size_t xn_bytes = (size_t)rows * D * sizeof(short);
  float* srow     = (float*)(ws + xn_bytes);           // [5][128][8][32]: 640 KiB
  float* scol     = srow + 5 * 128 * 8 * 32;           // [2][32][4096]: 1 MiB
  float* diag     = scol + 2 * 32 * BSZ;               // [5][4096]: 80 KiB
  unsigned int* ticket = (unsigned int*)(diag + 5 * BSZ);

  normalize_kernel<<<rows / 4, 256, 0, stream>>>(
      x, (__hip_bfloat162*)xnf, (float*)d_out, ticket, rows);
  expsim_kernel<<<GRID_EXPSIM, 256, 0, stream>>>(
      (const short8*)xnf, srow, scol, diag, (float*)d_out, ticket);
}

// Round 3
// 97.305 us; speedup vs baseline: 1.3089x; 1.0358x over previous
//
#include <hip/hip_runtime.h>
#include <hip/hip_bf16.h>

// ---------------------------------------------------------------------------
// LossNet: x (12288,128) fp32 -> scalar loss.  bsz=4096.
// 5 matrices (zx/zy folded into colsums of xz/yz):
//   task 0 xx, 1 yy, 2 xy, 3 xz (+colsum->s_zx), 4 yz (+colsum->s_zy)
// Fragment-native layout (R6): every MFMA A/B fragment is ONE coalesced
// global_load_dwordx4; no LDS staging, no hot-loop barriers.
// R17 = R14 3-kernel structure (measured best: 94.8 us) + float4 normalize.
// R15/R16 post-mortem (fused-reduce arc, CLOSED): per-block __threadfence
// (buffer_inv) evicted the shared xnf L2 set -> +38 us (R15); fence-free
// agent-scope protocol fixed that but the reducers' sc0/sc1 L2-BYPASS reads
// of srow/scol/diag are inherently slow, and fused expsim (48 us) only
// matched the expsim+gap+reduce sequence it replaced -> net +6 us (R16).
// Kernel-boundary writeback + cached reads is the cheapest coherence.
// R12/R13: triangular xx/yy is grid-quantization-bound -> regressed.
// The ~4 ns per 128x64-tile expsim constant survived six structure
// falsifications -> structural plateau.  Timed window is ~44% fixed
// harness poison fill (268 MB @ ~80% HBM peak).
// All reductions exclusive non-atomic stores (R3: atomics serialized).
// exp = __builtin_amdgcn_exp2f on prescaled inputs (1 inst).
// ---------------------------------------------------------------------------

typedef __attribute__((ext_vector_type(8))) short short8;   // 8 x bf16
typedef __attribute__((ext_vector_type(4))) float floatx4;  // MFMA acc

#define D   128
#define BSZ 4096
// expsim grid: 5 tasks x 32 rb(128 rows) x 8 cb(512 cols) = 1280 blocks
#define GRID_EXPSIM (5 * 32 * 8)

// ---------------------------------------------------------------------------
// Kernel 1: row-normalize fp32 -> bf16 into fragment-native layout,
// prescaled by sqrt(10*log2(e)).  R17: float4 loads (16 B/lane, the
// coalescing sweet spot) -- 32 lanes cover a row, each wave handles 2 rows,
// block handles 8.  5-step shuffle reduce (offsets <32 stay within the
// 32-lane row group).  Scatter: the two bf162 produced by one float4 land
// at adjacent jj,jj+1 slots of the same (g,kk,quad,row) group -> ONE
// aligned 8 B store per lane.  Also zeroes out[0].
// ---------------------------------------------------------------------------
struct alignas(8) bf162x2 { __hip_bfloat162 lo, hi; };

__global__ __launch_bounds__(256) void normalize_kernel(
    const float* __restrict__ x, __hip_bfloat162* __restrict__ xnf2,
    float* __restrict__ out, int rows) {
  int tid = threadIdx.x;
  if (blockIdx.x == 0 && tid == 0) out[0] = 0.0f;

  int row = blockIdx.x * 8 + (tid >> 5);
  int l5  = tid & 31;
  if (row >= rows) return;
  const float4* xr = (const float4*)(x + (size_t)row * D);
  float4 v = xr[l5];
  float s = v.x * v.x + v.y * v.y + v.z * v.z + v.w * v.w;
#pragma unroll
  for (int off = 1; off < 32; off <<= 1) s += __shfl_xor(s, off, 64);
  // sqrt(10 / ln 2): dot(a,b) = 10*log2(e)*cos -> e^(10 cos) = exp2(dot)
  float scale = 3.7982825470322528f / fmaxf(sqrtf(s), 1e-12f);
  bf162x2 h;
  h.lo.x = __float2bfloat16(v.x * scale);
  h.lo.y = __float2bfloat16(v.y * scale);
  h.hi.x = __float2bfloat16(v.z * scale);
  h.hi.y = __float2bfloat16(v.w * scale);
  // fragment-native scatter: k0 = l5*4
  // bf162 idx = g*1024 + (k0>>5)*256 + (((k0>>3)&3)*16 + (row&15))*4
  //             + (k0&7)/2   -> jj = (l5&1)*2, pair jj,jj+1 contiguous
  int g    = row >> 4;
  int kk   = l5 >> 3;              // k0>>5
  int quad = (l5 >> 1) & 3;        // (k0>>3)&3
  int jj   = (l5 & 1) * 2;         // (k0&7)/2
  *(bf162x2*)(xnf2 + g * 1024 + kk * 256 + (quad * 16 + (row & 15)) * 4 + jj) = h;
}

// ---------------------------------------------------------------------------
// 16-col subtile epilogue for a 32-row wave: 8 exps, rowsum adds, optional
// colsum (quad-reduce -> LDS slot, written once), diag when st==st0+mi.
// C/D layout: col=lm, row=quad*4+reg  [m89-verified]
// ---------------------------------------------------------------------------
template <bool COL>
__device__ __forceinline__ void epi16(
    const floatx4 (&ac)[2], float (&rs)[2][4], int st,
    bool dgw, int st0, int rowg0, int quad, int lm, int w,
    float* __restrict__ diag_ptr, float* __restrict__ csLDS) {
  float cs = 0.f;
#pragma unroll
  for (int mi = 0; mi < 2; mi++) {
    bool dd = dgw && (st == st0 + mi);   // wave-uniform
#pragma unroll
    for (int r = 0; r < 4; r++) {
      float e = __builtin_amdgcn_exp2f(ac[mi][r]);  // v_exp_f32
      rs[mi][r] += e;
      if (COL) cs += e;
      if (dd && lm == quad * 4 + r)
        diag_ptr[rowg0 + mi * 16 + quad * 4 + r] = e;
    }
  }
  if (COL) {
    cs += __shfl_xor(cs, 16, 64);
    cs += __shfl_xor(cs, 32, 64);
    if (quad == 0) csLDS[w * 512 + st * 16 + lm] = cs;
  }
}

#define MFMA8(AC, BF)                                                        \
  _Pragma("unroll") for (int kk = 0; kk < 4; kk++)                           \
      _Pragma("unroll") for (int mi = 0; mi < 2; mi++)                       \
          AC[mi] = __builtin_amdgcn_mfma_f32_16x16x32_bf16(                  \
              afrag[mi][kk], BF[kk], (kk == 0) ? z4 : AC[mi], 0, 0, 0);

// ---------------------------------------------------------------------------
// Wave main loop: 32 rows x 512 cols as 32 subtiles of 16 cols, software-
// pipelined (epi of s-1 between MFMAs of s / loads of s+1).
// ---------------------------------------------------------------------------
template <bool COL>
__device__ __forceinline__ void wave_loop(
    const short8* __restrict__ xnf8, int gA, int gB0, int rowg0,
    int st0, bool dgw, int quad, int lm, int w, int lane,
    float (&rs)[2][4], float* __restrict__ diag_ptr,
    float* __restrict__ csLDS) {
  const floatx4 z4 = {0.f, 0.f, 0.f, 0.f};

  short8 afrag[2][4];
#pragma unroll
  for (int mi = 0; mi < 2; mi++)
#pragma unroll
    for (int kk = 0; kk < 4; kk++)
      afrag[mi][kk] = xnf8[(size_t)(gA + mi) * 256 + kk * 64 + lane];

  const short8* bp = xnf8 + (size_t)gB0 * 256 + lane;
  short8 bf0[4], bf1[4];
#pragma unroll
  for (int kk = 0; kk < 4; kk++) bf0[kk] = bp[kk * 64];
#pragma unroll
  for (int kk = 0; kk < 4; kk++) bf1[kk] = bp[256 + kk * 64];

  floatx4 ac0[2], ac1[2];
  MFMA8(ac0, bf0)   // st 0

#pragma unroll 1
  for (int k = 0; k < 15; k++) {
    int sB = 2 * k + 2;
    MFMA8(ac1, bf1)   // st sB-1
#pragma unroll
    for (int kk = 0; kk < 4; kk++) bf0[kk] = bp[(size_t)sB * 256 + kk * 64];
    epi16<COL>(ac0, rs, sB - 2, dgw, st0, rowg0, quad, lm, w, diag_ptr, csLDS);
    MFMA8(ac0, bf0)   // st sB
#pragma unroll
    for (int kk = 0; kk < 4; kk++) bf1[kk] = bp[(size_t)(sB + 1) * 256 + kk * 64];
    epi16<COL>(ac1, rs, sB - 1, dgw, st0, rowg0, quad, lm, w, diag_ptr, csLDS);
  }
  // tail: st 31 from bf1; epi st 30 (ac0), st 31 (ac1)
  MFMA8(ac1, bf1)
  epi16<COL>(ac0, rs, 30, dgw, st0, rowg0, quad, lm, w, diag_ptr, csLDS);
  epi16<COL>(ac1, rs, 31, dgw, st0, rowg0, quad, lm, w, diag_ptr, csLDS);
}

// ---------------------------------------------------------------------------
// Kernel 2: exp-sim.  block = (task, rb of 128 rows, cb of 512 cols);
// wave w owns rows rb*128+w*32..+32, all 512 cols.  4 waves share B (L1).
// NOTE: plain __launch_bounds__(256) — min-waves cap spills (R2).
// ---------------------------------------------------------------------------
__global__ __launch_bounds__(256) void expsim_kernel(
    const short8* __restrict__ xnf8,
    float* __restrict__ srow,   // [5][128][8][32] exclusive
    float* __restrict__ scol,   // [2][32][4096] exclusive
    float* __restrict__ diag) { // [5][4096] exclusive
  __shared__ float csLDS[4 * 512];   // colsum accum, tasks 3-4 only

  int tid = threadIdx.x;
  int bx  = blockIdx.x;
  int task = bx >> 8;          // 256 blocks per task
  int rem  = bx & 255;
  int rb   = rem >> 3;         // 32 row-blocks of 128
  int cb   = rem & 7;          // 8 col-strips of 512

  const int aoff_t[5] = {0, 1, 0, 0, 1};
  const int boff_t[5] = {0, 1, 1, 2, 2};
  bool col_en = (task >= 3);

  int w    = tid >> 6;
  int lane = tid & 63;
  int quad = lane >> 4;
  int lm   = lane & 15;
  int rowg0 = rb * 128 + w * 32;

  int gA  = aoff_t[task] * 256 + rb * 8 + w * 2;
  int gB0 = boff_t[task] * 256 + cb * 32;
  int st0 = rb * 8 + w * 2 - cb * 32;   // diag subtile (mi=0) if in range
  bool dgw = (st0 >= 0 && st0 < 32);

  float* diag_ptr = diag + task * BSZ;

  float rs[2][4];
#pragma unroll
  for (int mi = 0; mi < 2; mi++)
#pragma unroll
    for (int r = 0; r < 4; r++) rs[mi][r] = 0.0f;

  if (col_en)
    wave_loop<true>(xnf8, gA, gB0, rowg0, st0, dgw, quad, lm, w, lane, rs,
                    diag_ptr, csLDS);
  else
    wave_loop<false>(xnf8, gA, gB0, rowg0, st0, dgw, quad, lm, w, lane, rs,
                     diag_ptr, csLDS);

  // ---- row-sum flush: reduce over lm within quad, exclusive store ----
  float* sp = srow + (((size_t)task * 128 + rb * 4 + w) * 8 + cb) * 32;
#pragma unroll
  for (int mi = 0; mi < 2; mi++) {
#pragma unroll
    for (int r = 0; r < 4; r++) {
      float v = rs[mi][r];
      v += __shfl_xor(v, 1, 64);
      v += __shfl_xor(v, 2, 64);
      v += __shfl_xor(v, 4, 64);
      v += __shfl_xor(v, 8, 64);
      if (lm == 0) sp[mi * 16 + quad * 4 + r] = v;
    }
  }

  // ---- col-sum flush: one barrier, cross-wave LDS reduce, exclusive ----
  if (col_en) {
    __syncthreads();
    float* scp = scol + ((size_t)((task - 3) * 32 + rb)) * BSZ + cb * 512;
    for (int c = tid; c < 512; c += 256)
      scp[c] = csLDS[c] + csLDS[512 + c] + csLDS[1024 + c] + csLDS[1536 + c];
  }
}

// ---------------------------------------------------------------------------
// Kernel 3: final loss reduction.  16 blocks x 256 threads, one row each.
// ---------------------------------------------------------------------------
__global__ __launch_bounds__(256) void reduce_kernel(
    const float* __restrict__ srow, const float* __restrict__ scol,
    const float* __restrict__ diag, float* __restrict__ out) {
  int tid = threadIdx.x;
  int i   = blockIdx.x * 256 + tid;
  int strip = i >> 5, rloc = i & 31;

  float s[5];
#pragma unroll
  for (int t = 0; t < 5; t++) {
    float a = 0.f;
#pragma unroll
    for (int cb = 0; cb < 8; cb++)
      a += srow[(((size_t)t * 128 + strip) * 8 + cb) * 32 + rloc];
    s[t] = a;
  }
  float s_zx = 0.f, s_zy = 0.f;
#pragma unroll 8
  for (int rb = 0; rb < 32; rb++) {
    s_zx += scol[(size_t)rb * BSZ + i];
    s_zy += scol[(size_t)(32 + rb) * BSZ + i];
  }
  float d_xx = diag[0 * BSZ + i], d_yy = diag[1 * BSZ + i];
  float d_xy = diag[2 * BSZ + i], d_ax = diag[3 * BSZ + i];
  float d_ay = diag[4 * BSZ + i];

  float denom = (s[2] - d_xy) + (s[0] - d_xx) + (s[1] - d_yy);
  float tloc = -2.0f * __logf(d_xy / denom);
  tloc -= __logf(d_ax / (s[3] - d_ax));
  tloc -= __logf(d_ay / (s[4] - d_ay));
  tloc -= __logf(d_ax / (s_zx - d_ax));   // d_zx == d_ax
  tloc -= __logf(d_ay / (s_zy - d_ay));   // d_zy == d_ay

  __shared__ float red[256];
  red[tid] = tloc;
  __syncthreads();
  for (int st = 128; st > 0; st >>= 1) {
    if (tid < st) red[tid] += red[tid + st];
    __syncthreads();
  }
  if (tid == 0) atomicAdd(out, red[0] / (float)BSZ);
}

// ---------------------------------------------------------------------------
extern "C" void kernel_launch(void* const* d_in, const int* in_sizes, int n_in,
                              void* d_out, int out_size, void* d_ws, size_t ws_size,
                              hipStream_t stream) {
  const float* x = (const float*)d_in[0];
  int rows = in_sizes[0] / D;   // 12288

  char*  ws       = (char*)d_ws;
  short* xnf      = (short*)ws;                        // 12288*128 bf16: 3 MiB
  size_t xn_bytes = (size_t)rows * D * sizeof(short);
  float* srow     = (float*)(ws + xn_bytes);           // [5][128][8][32]: 640 KiB
  float* scol     = srow + 5 * 128 * 8 * 32;           // [2][32][4096]: 1 MiB
  float* diag     = scol + 2 * 32 * BSZ;               // [5][4096]: 80 KiB

  normalize_kernel<<<rows / 8, 256, 0, stream>>>(
      x, (__hip_bfloat162*)xnf, (float*)d_out, rows);
  expsim_kernel<<<GRID_EXPSIM, 256, 0, stream>>>(
      (const short8*)xnf, srow, scol, diag);
  reduce_kernel<<<16, 256, 0, stream>>>(srow, scol, diag, (float*)d_out);
}

// Round 4
// 95.909 us; speedup vs baseline: 1.3280x; 1.0146x over previous
//
#include <hip/hip_runtime.h>
#include <hip/hip_bf16.h>

// ---------------------------------------------------------------------------
// LossNet: x (12288,128) fp32 -> scalar loss.  bsz=4096.
// 5 matrices (zx/zy folded into colsums of xz/yz):
//   task 0 xx, 1 yy, 2 xy, 3 xz (+colsum->s_zx), 4 yz (+colsum->s_zy)
// Fragment-native layout (R6): every MFMA A/B fragment is ONE coalesced
// global_load_dwordx4; no LDS staging, no hot-loop barriers.
// R18 = R14 VERBATIM (measured best: 94.2 / 94.8 us).  Closed arcs:
//  - R15/R16 fused reduce: per-block __threadfence (buffer_inv) evicted the
//    shared xnf L2 set (+38 us); fence-free agent-scope fix only matched the
//    3-kernel sequence (sc0/sc1 reads bypass L2) -> net +6 us.  Kernel-
//    boundary writeback + cached reads is the cheapest coherence.
//  - R17 float4 normalize: 97.3 vs 94.8 -> not reproducibly better.
//  - R12/R13 triangular xx/yy: grid-quantization-bound -> regressed.
//  - Expsim hot loop: ~4 ns per 128x64 tile survived six structure
//    falsifications (LDS-staged / direct / prefetch / reuse / pipelined /
//    64-row waves) -> structural plateau.
// Timed window is ~44% fixed harness poison fill (268 MB @ ~80% HBM peak).
// All reductions exclusive non-atomic stores (R3: atomics serialized).
// exp = __builtin_amdgcn_exp2f on prescaled inputs (1 inst).
// ---------------------------------------------------------------------------

typedef __attribute__((ext_vector_type(8))) short short8;   // 8 x bf16
typedef __attribute__((ext_vector_type(4))) float floatx4;  // MFMA acc

#define D   128
#define BSZ 4096
// expsim grid: 5 tasks x 32 rb(128 rows) x 8 cb(512 cols) = 1280 blocks
#define GRID_EXPSIM (5 * 32 * 8)

// ---------------------------------------------------------------------------
// Kernel 1: row-normalize fp32 -> bf16 into fragment-native layout,
// prescaled by sqrt(10*log2(e)).  One wave per row.  Also zeroes out[0].
// ---------------------------------------------------------------------------
__global__ __launch_bounds__(256) void normalize_kernel(
    const float* __restrict__ x, __hip_bfloat162* __restrict__ xnf2,
    float* __restrict__ out, int rows) {
  int tid = threadIdx.x;
  if (blockIdx.x == 0 && tid == 0) out[0] = 0.0f;

  int row  = blockIdx.x * 4 + (tid >> 6);
  int lane = tid & 63;
  if (row >= rows) return;
  const float2* xr = (const float2*)(x + (size_t)row * D);
  float2 v = xr[lane];
  float s = v.x * v.x + v.y * v.y;
#pragma unroll
  for (int off = 1; off < 64; off <<= 1) s += __shfl_xor(s, off, 64);
  // sqrt(10 / ln 2): dot(a,b) = 10*log2(e)*cos -> e^(10 cos) = exp2(dot)
  float scale = 3.7982825470322528f / fmaxf(sqrtf(s), 1e-12f);
  __hip_bfloat162 h;
  h.x = __float2bfloat16(v.x * scale);
  h.y = __float2bfloat16(v.y * scale);
  // fragment-native scatter: k0 = lane*2
  // short idx = g*2048 + kk*512 + (quad*16 + (row&15))*8 + j   (as bf162: /2)
  int g    = row >> 4;
  int kk   = lane >> 4;            // k0>>5
  int quad = (lane >> 2) & 3;      // (k0>>3)&3
  int jj   = lane & 3;             // (k0&7)/2
  xnf2[g * 1024 + kk * 256 + (quad * 16 + (row & 15)) * 4 + jj] = h;
}

// ---------------------------------------------------------------------------
// 16-col subtile epilogue for a 32-row wave: 8 exps, rowsum adds, optional
// colsum (quad-reduce -> LDS slot, written once), diag when st==st0+mi.
// C/D layout: col=lm, row=quad*4+reg  [m89-verified]
// ---------------------------------------------------------------------------
template <bool COL>
__device__ __forceinline__ void epi16(
    const floatx4 (&ac)[2], float (&rs)[2][4], int st,
    bool dgw, int st0, int rowg0, int quad, int lm, int w,
    float* __restrict__ diag_ptr, float* __restrict__ csLDS) {
  float cs = 0.f;
#pragma unroll
  for (int mi = 0; mi < 2; mi++) {
    bool dd = dgw && (st == st0 + mi);   // wave-uniform
#pragma unroll
    for (int r = 0; r < 4; r++) {
      float e = __builtin_amdgcn_exp2f(ac[mi][r]);  // v_exp_f32
      rs[mi][r] += e;
      if (COL) cs += e;
      if (dd && lm == quad * 4 + r)
        diag_ptr[rowg0 + mi * 16 + quad * 4 + r] = e;
    }
  }
  if (COL) {
    cs += __shfl_xor(cs, 16, 64);
    cs += __shfl_xor(cs, 32, 64);
    if (quad == 0) csLDS[w * 512 + st * 16 + lm] = cs;
  }
}

#define MFMA8(AC, BF)                                                        \
  _Pragma("unroll") for (int kk = 0; kk < 4; kk++)                           \
      _Pragma("unroll") for (int mi = 0; mi < 2; mi++)                       \
          AC[mi] = __builtin_amdgcn_mfma_f32_16x16x32_bf16(                  \
              afrag[mi][kk], BF[kk], (kk == 0) ? z4 : AC[mi], 0, 0, 0);

// ---------------------------------------------------------------------------
// Wave main loop: 32 rows x 512 cols as 32 subtiles of 16 cols, software-
// pipelined (epi of s-1 between MFMAs of s / loads of s+1).
// ---------------------------------------------------------------------------
template <bool COL>
__device__ __forceinline__ void wave_loop(
    const short8* __restrict__ xnf8, int gA, int gB0, int rowg0,
    int st0, bool dgw, int quad, int lm, int w, int lane,
    float (&rs)[2][4], float* __restrict__ diag_ptr,
    float* __restrict__ csLDS) {
  const floatx4 z4 = {0.f, 0.f, 0.f, 0.f};

  short8 afrag[2][4];
#pragma unroll
  for (int mi = 0; mi < 2; mi++)
#pragma unroll
    for (int kk = 0; kk < 4; kk++)
      afrag[mi][kk] = xnf8[(size_t)(gA + mi) * 256 + kk * 64 + lane];

  const short8* bp = xnf8 + (size_t)gB0 * 256 + lane;
  short8 bf0[4], bf1[4];
#pragma unroll
  for (int kk = 0; kk < 4; kk++) bf0[kk] = bp[kk * 64];
#pragma unroll
  for (int kk = 0; kk < 4; kk++) bf1[kk] = bp[256 + kk * 64];

  floatx4 ac0[2], ac1[2];
  MFMA8(ac0, bf0)   // st 0

#pragma unroll 1
  for (int k = 0; k < 15; k++) {
    int sB = 2 * k + 2;
    MFMA8(ac1, bf1)   // st sB-1
#pragma unroll
    for (int kk = 0; kk < 4; kk++) bf0[kk] = bp[(size_t)sB * 256 + kk * 64];
    epi16<COL>(ac0, rs, sB - 2, dgw, st0, rowg0, quad, lm, w, diag_ptr, csLDS);
    MFMA8(ac0, bf0)   // st sB
#pragma unroll
    for (int kk = 0; kk < 4; kk++) bf1[kk] = bp[(size_t)(sB + 1) * 256 + kk * 64];
    epi16<COL>(ac1, rs, sB - 1, dgw, st0, rowg0, quad, lm, w, diag_ptr, csLDS);
  }
  // tail: st 31 from bf1; epi st 30 (ac0), st 31 (ac1)
  MFMA8(ac1, bf1)
  epi16<COL>(ac0, rs, 30, dgw, st0, rowg0, quad, lm, w, diag_ptr, csLDS);
  epi16<COL>(ac1, rs, 31, dgw, st0, rowg0, quad, lm, w, diag_ptr, csLDS);
}

// ---------------------------------------------------------------------------
// Kernel 2: exp-sim.  block = (task, rb of 128 rows, cb of 512 cols);
// wave w owns rows rb*128+w*32..+32, all 512 cols.  4 waves share B (L1).
// NOTE: plain __launch_bounds__(256) — min-waves cap spills (R2).
// ---------------------------------------------------------------------------
__global__ __launch_bounds__(256) void expsim_kernel(
    const short8* __restrict__ xnf8,
    float* __restrict__ srow,   // [5][128][8][32] exclusive
    float* __restrict__ scol,   // [2][32][4096] exclusive
    float* __restrict__ diag) { // [5][4096] exclusive
  __shared__ float csLDS[4 * 512];   // colsum accum, tasks 3-4 only

  int tid = threadIdx.x;
  int bx  = blockIdx.x;
  int task = bx >> 8;          // 256 blocks per task
  int rem  = bx & 255;
  int rb   = rem >> 3;         // 32 row-blocks of 128
  int cb   = rem & 7;          // 8 col-strips of 512

  const int aoff_t[5] = {0, 1, 0, 0, 1};
  const int boff_t[5] = {0, 1, 1, 2, 2};
  bool col_en = (task >= 3);

  int w    = tid >> 6;
  int lane = tid & 63;
  int quad = lane >> 4;
  int lm   = lane & 15;
  int rowg0 = rb * 128 + w * 32;

  int gA  = aoff_t[task] * 256 + rb * 8 + w * 2;
  int gB0 = boff_t[task] * 256 + cb * 32;
  int st0 = rb * 8 + w * 2 - cb * 32;   // diag subtile (mi=0) if in range
  bool dgw = (st0 >= 0 && st0 < 32);

  float* diag_ptr = diag + task * BSZ;

  float rs[2][4];
#pragma unroll
  for (int mi = 0; mi < 2; mi++)
#pragma unroll
    for (int r = 0; r < 4; r++) rs[mi][r] = 0.0f;

  if (col_en)
    wave_loop<true>(xnf8, gA, gB0, rowg0, st0, dgw, quad, lm, w, lane, rs,
                    diag_ptr, csLDS);
  else
    wave_loop<false>(xnf8, gA, gB0, rowg0, st0, dgw, quad, lm, w, lane, rs,
                     diag_ptr, csLDS);

  // ---- row-sum flush: reduce over lm within quad, exclusive store ----
  float* sp = srow + (((size_t)task * 128 + rb * 4 + w) * 8 + cb) * 32;
#pragma unroll
  for (int mi = 0; mi < 2; mi++) {
#pragma unroll
    for (int r = 0; r < 4; r++) {
      float v = rs[mi][r];
      v += __shfl_xor(v, 1, 64);
      v += __shfl_xor(v, 2, 64);
      v += __shfl_xor(v, 4, 64);
      v += __shfl_xor(v, 8, 64);
      if (lm == 0) sp[mi * 16 + quad * 4 + r] = v;
    }
  }

  // ---- col-sum flush: one barrier, cross-wave LDS reduce, exclusive ----
  if (col_en) {
    __syncthreads();
    float* scp = scol + ((size_t)((task - 3) * 32 + rb)) * BSZ + cb * 512;
    for (int c = tid; c < 512; c += 256)
      scp[c] = csLDS[c] + csLDS[512 + c] + csLDS[1024 + c] + csLDS[1536 + c];
  }
}

// ---------------------------------------------------------------------------
// Kernel 3: final loss reduction.  16 blocks x 256 threads, one row each.
// ---------------------------------------------------------------------------
__global__ __launch_bounds__(256) void reduce_kernel(
    const float* __restrict__ srow, const float* __restrict__ scol,
    const float* __restrict__ diag, float* __restrict__ out) {
  int tid = threadIdx.x;
  int i   = blockIdx.x * 256 + tid;
  int strip = i >> 5, rloc = i & 31;

  float s[5];
#pragma unroll
  for (int t = 0; t < 5; t++) {
    float a = 0.f;
#pragma unroll
    for (int cb = 0; cb < 8; cb++)
      a += srow[(((size_t)t * 128 + strip) * 8 + cb) * 32 + rloc];
    s[t] = a;
  }
  float s_zx = 0.f, s_zy = 0.f;
#pragma unroll 8
  for (int rb = 0; rb < 32; rb++) {
    s_zx += scol[(size_t)rb * BSZ + i];
    s_zy += scol[(size_t)(32 + rb) * BSZ + i];
  }
  float d_xx = diag[0 * BSZ + i], d_yy = diag[1 * BSZ + i];
  float d_xy = diag[2 * BSZ + i], d_ax = diag[3 * BSZ + i];
  float d_ay = diag[4 * BSZ + i];

  float denom = (s[2] - d_xy) + (s[0] - d_xx) + (s[1] - d_yy);
  float tloc = -2.0f * __logf(d_xy / denom);
  tloc -= __logf(d_ax / (s[3] - d_ax));
  tloc -= __logf(d_ay / (s[4] - d_ay));
  tloc -= __logf(d_ax / (s_zx - d_ax));   // d_zx == d_ax
  tloc -= __logf(d_ay / (s_zy - d_ay));   // d_zy == d_ay

  __shared__ float red[256];
  red[tid] = tloc;
  __syncthreads();
  for (int st = 128; st > 0; st >>= 1) {
    if (tid < st) red[tid] += red[tid + st];
    __syncthreads();
  }
  if (tid == 0) atomicAdd(out, red[0] / (float)BSZ);
}

// ---------------------------------------------------------------------------
extern "C" void kernel_launch(void* const* d_in, const int* in_sizes, int n_in,
                              void* d_out, int out_size, void* d_ws, size_t ws_size,
                              hipStream_t stream) {
  const float* x = (const float*)d_in[0];
  int rows = in_sizes[0] / D;   // 12288

  char*  ws       = (char*)d_ws;
  short* xnf      = (short*)ws;                        // 12288*128 bf16: 3 MiB
  size_t xn_bytes = (size_t)rows * D * sizeof(short);
  float* srow     = (float*)(ws + xn_bytes);           // [5][128][8][32]: 640 KiB
  float* scol     = srow + 5 * 128 * 8 * 32;           // [2][32][4096]: 1 MiB
  float* diag     = scol + 2 * 32 * BSZ;               // [5][4096]: 80 KiB

  normalize_kernel<<<rows / 4, 256, 0, stream>>>(
      x, (__hip_bfloat162*)xnf, (float*)d_out, rows);
  expsim_kernel<<<GRID_EXPSIM, 256, 0, stream>>>(
      (const short8*)xnf, srow, scol, diag);
  reduce_kernel<<<16, 256, 0, stream>>>(srow, scol, diag, (float*)d_out);
}